// Round 1
// baseline (180.255 us; speedup 1.0000x reference)
//
#include <hip/hip_runtime.h>
#include <math.h>

#define EPS 1e-6f

constexpr int B  = 8;
constexpr int F  = 64;
constexpr int C  = 16;
constexpr int L  = 65536;       // 256*256
constexpr int G4 = L / 4;       // 16384 float4 groups per (b, f) slice
constexpr int TPB = 256;

// Stage 1: partial sums num[term][b][c] = sum_l (e2 - 2*dot)*r, den = sum_l r.
// ws layout: float ws[2][2][B][C]  -> [term][num/den][b][c]
__global__ __launch_bounds__(TPB)
void cross_partial_kernel(const float* __restrict__ embed1,
                          const float* __restrict__ rids1,
                          const float* __restrict__ embed2,
                          const float* __restrict__ rids2,
                          const float* __restrict__ codebook,
                          float* __restrict__ ws)
{
    __shared__ float cbs[F * C];
    const int tid = threadIdx.x;
    // codebook (64x16 f32 = 4KB) -> LDS, one float4 per thread
    ((float4*)cbs)[tid] = ((const float4*)codebook)[tid];
    __syncthreads();

    const int term = blockIdx.z;          // 0: (embed_1, r_ids_2), 1: (embed_2, r_ids_1)
    const int b    = blockIdx.y;
    const float* eptr = (term == 0) ? embed1 : embed2;
    const float* rptr = (term == 0) ? rids2  : rids1;

    const int g = blockIdx.x * TPB + tid;                      // float4-group in [0, G4)
    const float4* eb   = (const float4*)(eptr + (size_t)b * F * L) + g;
    const float4* rb   = (const float4*)(rptr + (size_t)b * C * L) + g;
    const float4* cbs4 = (const float4*)cbs;

    float dotv[C][4];
    #pragma unroll
    for (int c = 0; c < C; ++c)
        dotv[c][0] = dotv[c][1] = dotv[c][2] = dotv[c][3] = 0.f;
    float e2x = 0.f, e2y = 0.f, e2z = 0.f, e2w = 0.f;

    #pragma unroll 4
    for (int f = 0; f < F; ++f) {
        const float4 e4 = eb[(size_t)f * G4];
        e2x = fmaf(e4.x, e4.x, e2x);
        e2y = fmaf(e4.y, e4.y, e2y);
        e2z = fmaf(e4.z, e4.z, e2z);
        e2w = fmaf(e4.w, e4.w, e2w);
        #pragma unroll
        for (int q = 0; q < 4; ++q) {
            const float4 w = cbs4[f * 4 + q];   // cb[f][4q..4q+3], wave-uniform broadcast
            dotv[q*4+0][0] = fmaf(e4.x, w.x, dotv[q*4+0][0]);
            dotv[q*4+0][1] = fmaf(e4.y, w.x, dotv[q*4+0][1]);
            dotv[q*4+0][2] = fmaf(e4.z, w.x, dotv[q*4+0][2]);
            dotv[q*4+0][3] = fmaf(e4.w, w.x, dotv[q*4+0][3]);
            dotv[q*4+1][0] = fmaf(e4.x, w.y, dotv[q*4+1][0]);
            dotv[q*4+1][1] = fmaf(e4.y, w.y, dotv[q*4+1][1]);
            dotv[q*4+1][2] = fmaf(e4.z, w.y, dotv[q*4+1][2]);
            dotv[q*4+1][3] = fmaf(e4.w, w.y, dotv[q*4+1][3]);
            dotv[q*4+2][0] = fmaf(e4.x, w.z, dotv[q*4+2][0]);
            dotv[q*4+2][1] = fmaf(e4.y, w.z, dotv[q*4+2][1]);
            dotv[q*4+2][2] = fmaf(e4.z, w.z, dotv[q*4+2][2]);
            dotv[q*4+2][3] = fmaf(e4.w, w.z, dotv[q*4+2][3]);
            dotv[q*4+3][0] = fmaf(e4.x, w.w, dotv[q*4+3][0]);
            dotv[q*4+3][1] = fmaf(e4.y, w.w, dotv[q*4+3][1]);
            dotv[q*4+3][2] = fmaf(e4.z, w.w, dotv[q*4+3][2]);
            dotv[q*4+3][3] = fmaf(e4.w, w.w, dotv[q*4+3][3]);
        }
    }

    // epilogue: fold r, wave-reduce, one atomic per wave per (c, num/den)
    const int lane = tid & 63;
    float* wsn = ws + ((size_t)(term * 2 + 0) * B + b) * C;
    float* wsd = ws + ((size_t)(term * 2 + 1) * B + b) * C;
    #pragma unroll
    for (int c = 0; c < C; ++c) {
        const float4 r4 = rb[(size_t)c * G4];
        const float sx = fmaf(-2.f, dotv[c][0], e2x);
        const float sy = fmaf(-2.f, dotv[c][1], e2y);
        const float sz = fmaf(-2.f, dotv[c][2], e2z);
        const float sw = fmaf(-2.f, dotv[c][3], e2w);
        float num = fmaf(sx, r4.x, fmaf(sy, r4.y, fmaf(sz, r4.z, sw * r4.w)));
        float den = (r4.x + r4.y) + (r4.z + r4.w);
        #pragma unroll
        for (int off = 32; off > 0; off >>= 1) {
            num += __shfl_down(num, off, 64);
            den += __shfl_down(den, off, 64);
        }
        if (lane == 0) {
            atomicAdd(&wsn[c], num);
            atomicAdd(&wsd[c], den);
        }
    }
}

// Stage 2: single block. cross = (num + cb2[c]*den)/(den+EPS); plus dist/reg losses.
__global__ __launch_bounds__(256)
void finalize_kernel(const float* __restrict__ codebook,
                     const float* __restrict__ ws,
                     float* __restrict__ out)
{
    __shared__ float cbs[F * C];
    __shared__ float cb2[C];
    __shared__ float red[256];
    __shared__ float redv[256];
    const int tid = threadIdx.x;
    ((float4*)cbs)[tid] = ((const float4*)codebook)[tid];
    __syncthreads();
    if (tid < C) {
        float s = 0.f;
        for (int f = 0; f < F; ++f) { const float v = cbs[f * C + tid]; s = fmaf(v, v, s); }
        cb2[tid] = s;
    }
    __syncthreads();

    // l_cross: 256 entries = [term(2)][b(8)][c(16)]
    {
        const int term = tid >> 7, rem = tid & 127;
        const int b = rem >> 4, c = rem & 15;
        const float num = ws[((size_t)(term * 2 + 0) * B + b) * C + c];
        const float den = ws[((size_t)(term * 2 + 1) * B + b) * C + c];
        const bool valid = (den != 0.f);
        red[tid]  = valid ? (num + cb2[c] * den) / (den + EPS) : 0.f;
        redv[tid] = valid ? 1.f : 0.f;
    }
    __syncthreads();
    if (tid == 0) {
        float s0 = 0.f, n0 = 0.f, s1 = 0.f, n1 = 0.f;
        for (int i = 0;   i < 128; ++i) { s0 += red[i]; n0 += redv[i]; }
        for (int i = 128; i < 256; ++i) { s1 += red[i]; n1 += redv[i]; }
        out[0] = s0 / n0 + s1 / n1;
    }
    __syncthreads();

    // l_dist: 256 (ci,cj) pairs, diagonal included exactly as reference (dist=0 -> hinge=4)
    {
        const int ci = tid & 15, cj = tid >> 4;
        float sq = 0.f;
        for (int f = 0; f < F; ++f) {
            const float d = cbs[f * C + ci] - cbs[f * C + cj];
            sq = fmaf(d, d, sq);
        }
        const float dist = (sq > 0.f) ? sqrtf(sq) : 0.f;
        const float h = fmaxf(2.f * 1.0f - dist, 0.f);
        red[tid] = h * h;
    }
    __syncthreads();
    if (tid == 0) {
        float s = 0.f;
        for (int i = 0; i < 256; ++i) s += red[i];
        out[1] = s / (2.f * C * (C - 1));
        float rg = 0.f;
        for (int c = 0; c < C; ++c) rg += sqrtf(cb2[c]);
        out[2] = rg / C;
    }
}

extern "C" void kernel_launch(void* const* d_in, const int* in_sizes, int n_in,
                              void* d_out, int out_size, void* d_ws, size_t ws_size,
                              hipStream_t stream)
{
    const float* e1 = (const float*)d_in[0];
    const float* r1 = (const float*)d_in[1];
    const float* e2 = (const float*)d_in[2];
    const float* r2 = (const float*)d_in[3];
    const float* cb = (const float*)d_in[4];
    float* out = (float*)d_out;
    float* ws  = (float*)d_ws;

    // zero the 2*2*B*C accumulator block (d_ws is poisoned, not re-poisoned between replays)
    hipMemsetAsync(ws, 0, (size_t)2 * 2 * B * C * sizeof(float), stream);

    dim3 grid(G4 / TPB, B, 2);   // 64 x 8 x 2 = 1024 blocks
    cross_partial_kernel<<<grid, TPB, 0, stream>>>(e1, r1, e2, r2, cb, ws);
    finalize_kernel<<<1, 256, 0, stream>>>(cb, ws, out);
}

// Round 2
// 94.655 us; speedup vs baseline: 1.9043x; 1.9043x over previous
//
#include <hip/hip_runtime.h>
#include <math.h>

#define EPS 1e-6f

constexpr int B    = 8;
constexpr int F    = 64;
constexpr int C    = 16;
constexpr int L    = 65536;     // 256*256
constexpr int TPB  = 256;
constexpr int NREP = 8;         // atomic-target replicas to spread contention

// Stage 1: partials num[b,c] = sum_l (e2 - 2*dot)*r, den[b,c] = sum_l r.
// ws layout: float ws[NREP][2][2][B][C] -> [rep][term][num/den][b][c]
__global__ __launch_bounds__(TPB)
void cross_partial_kernel(const float* __restrict__ embed1,
                          const float* __restrict__ rids1,
                          const float* __restrict__ embed2,
                          const float* __restrict__ rids2,
                          const float* __restrict__ codebook,
                          float* __restrict__ ws)
{
    const int tid  = threadIdx.x;
    const int term = blockIdx.z;          // 0: (embed_1, r_ids_2), 1: (embed_2, r_ids_1)
    const int b    = blockIdx.y;
    const float* eptr = (term == 0) ? embed1 : embed2;
    const float* rptr = (term == 0) ? rids2  : rids1;

    const int l = blockIdx.x * TPB + tid;              // one spatial point per thread
    const float* eb = eptr + (size_t)b * F * L + l;
    const float* rb = rptr + (size_t)b * C * L + l;

    float dot[C];
    #pragma unroll
    for (int c = 0; c < C; ++c) dot[c] = 0.f;
    float e2 = 0.f;

    // 64 independent scalar loads; codebook reads are wave-uniform -> s_load/SGPR,
    // so the inner fma is v_fmac v, s, v with zero LDS traffic.
    #pragma unroll 8
    for (int f = 0; f < F; ++f) {
        const float e = eb[(size_t)f * L];
        e2 = fmaf(e, e, e2);
        #pragma unroll
        for (int c = 0; c < C; ++c)
            dot[c] = fmaf(e, codebook[f * C + c], dot[c]);
    }

    // fold r, wave shuffle-reduce, block LDS reduce, one atomic per block per value
    const int lane = tid & 63, wid = tid >> 6;
    __shared__ float part[4][2][C];
    #pragma unroll
    for (int c = 0; c < C; ++c) {
        const float r = rb[(size_t)c * L];
        float num = fmaf(-2.f, dot[c], e2) * r;
        float den = r;
        #pragma unroll
        for (int off = 32; off > 0; off >>= 1) {
            num += __shfl_down(num, off, 64);
            den += __shfl_down(den, off, 64);
        }
        if (lane == 0) { part[wid][0][c] = num; part[wid][1][c] = den; }
    }
    __syncthreads();
    if (tid < 2 * C) {
        const int p = tid >> 4, c = tid & 15;
        const float v = part[0][p][c] + part[1][p][c] + part[2][p][c] + part[3][p][c];
        const int rep = blockIdx.x & (NREP - 1);
        atomicAdd(ws + ((((size_t)rep * 2 + term) * 2 + p) * B + b) * C + c, v);
    }
}

// Stage 2: single block. cross = (num + cb2[c]*den)/(den+EPS); plus dist/reg losses.
__global__ __launch_bounds__(256)
void finalize_kernel(const float* __restrict__ codebook,
                     const float* __restrict__ ws,
                     float* __restrict__ out)
{
    __shared__ float cbs[F * C];
    __shared__ float cb2[C];
    __shared__ float red[256];
    __shared__ float redv[256];
    const int tid = threadIdx.x;
    ((float4*)cbs)[tid] = ((const float4*)codebook)[tid];
    __syncthreads();
    if (tid < C) {
        float s = 0.f;
        for (int f = 0; f < F; ++f) { const float v = cbs[f * C + tid]; s = fmaf(v, v, s); }
        cb2[tid] = s;
    }
    __syncthreads();

    // l_cross: 256 entries = [term(2)][b(8)][c(16)]
    {
        const int term = tid >> 7, rem = tid & 127;
        const int b = rem >> 4, c = rem & 15;
        float num = 0.f, den = 0.f;
        for (int rep = 0; rep < NREP; ++rep) {
            num += ws[((((size_t)rep * 2 + term) * 2 + 0) * B + b) * C + c];
            den += ws[((((size_t)rep * 2 + term) * 2 + 1) * B + b) * C + c];
        }
        const bool valid = (den != 0.f);
        red[tid]  = valid ? (num + cb2[c] * den) / (den + EPS) : 0.f;
        redv[tid] = valid ? 1.f : 0.f;
    }
    __syncthreads();
    if (tid == 0) {
        float s0 = 0.f, n0 = 0.f, s1 = 0.f, n1 = 0.f;
        for (int i = 0;   i < 128; ++i) { s0 += red[i]; n0 += redv[i]; }
        for (int i = 128; i < 256; ++i) { s1 += red[i]; n1 += redv[i]; }
        out[0] = s0 / n0 + s1 / n1;
    }
    __syncthreads();

    // l_dist: 256 (ci,cj) pairs, diagonal included exactly as reference
    {
        const int ci = tid & 15, cj = tid >> 4;
        float sq = 0.f;
        for (int f = 0; f < F; ++f) {
            const float d = cbs[f * C + ci] - cbs[f * C + cj];
            sq = fmaf(d, d, sq);
        }
        const float dist = (sq > 0.f) ? sqrtf(sq) : 0.f;
        const float h = fmaxf(2.f * 1.0f - dist, 0.f);
        red[tid] = h * h;
    }
    __syncthreads();
    if (tid == 0) {
        float s = 0.f;
        for (int i = 0; i < 256; ++i) s += red[i];
        out[1] = s / (2.f * C * (C - 1));
        float rg = 0.f;
        for (int c = 0; c < C; ++c) rg += sqrtf(cb2[c]);
        out[2] = rg / C;
    }
}

extern "C" void kernel_launch(void* const* d_in, const int* in_sizes, int n_in,
                              void* d_out, int out_size, void* d_ws, size_t ws_size,
                              hipStream_t stream)
{
    const float* e1 = (const float*)d_in[0];
    const float* r1 = (const float*)d_in[1];
    const float* e2 = (const float*)d_in[2];
    const float* r2 = (const float*)d_in[3];
    const float* cb = (const float*)d_in[4];
    float* out = (float*)d_out;
    float* ws  = (float*)d_ws;

    // zero the NREP*2*2*B*C accumulator block (16 KB)
    hipMemsetAsync(ws, 0, (size_t)NREP * 2 * 2 * B * C * sizeof(float), stream);

    dim3 grid(L / TPB, B, 2);   // 256 x 8 x 2 = 4096 blocks, 16384 waves
    cross_partial_kernel<<<grid, TPB, 0, stream>>>(e1, r1, e2, r2, cb, ws);
    finalize_kernel<<<1, 256, 0, stream>>>(cb, ws, out);
}